// Round 6
// baseline (2378.450 us; speedup 1.0000x reference)
//
#include <hip/hip_runtime.h>

#define B_ 16
#define T_ 128
#define H_ 512
#define V_ 50257
#define VP_ 50304            // 393*128 (padded V)
#define NBLK 393             // VP_/128
#define M_ (B_*T_)           // 2048 rows (t*16+b)
#define N4H 2048             // 4*H
#define KH 512               // K of hidden GEMMs
#define NKB 16               // KH/32
#define FP_ 32               // flag pad (ints) = 128 B per flag line
#define NTILES (NBLK * 16)   // 6288 logits tiles
#define NWORK 224            // logits worker blocks (32..255)

typedef __attribute__((ext_vector_type(8))) short short8;   // bf16x8 frag
typedef __attribute__((ext_vector_type(4))) float floatx4;
typedef unsigned long long u64;

static __device__ __forceinline__ unsigned short f2bf(float f) {
    unsigned int u = __builtin_bit_cast(unsigned int, f);
    unsigned int r = (u + 0x7FFFu + ((u >> 16) & 1u)) >> 16;
    return (unsigned short)r;
}
static __device__ __forceinline__ u64 ld_ic(const u64* p) {   // IC-coherent 8B load
    return __hip_atomic_load(p, __ATOMIC_RELAXED, __HIP_MEMORY_SCOPE_AGENT);
}
static __device__ __forceinline__ void st_ic(u64* p, u64 v) { // IC-coherent 8B store
    __hip_atomic_store(p, v, __ATOMIC_RELAXED, __HIP_MEMORY_SCOPE_AGENT);
}
static __device__ __forceinline__ short8 mk_frag(u64 a, u64 b) {
    union { u64 u[2]; short8 s8; } cv;
    cv.u[0] = a; cv.u[1] = b;
    return cv.s8;
}

// ---------------- init ----------------
__global__ void k_init(const int* __restrict__ labels, int* __restrict__ lab_r,
                       unsigned short* __restrict__ zeroh, int* __restrict__ flags) {
    int tid = blockIdx.x * blockDim.x + threadIdx.x;
    if (tid < M_) {
        int t = tid >> 4, b = tid & 15;
        lab_r[tid] = labels[b * T_ + t];   // row order is t*16+b; labels flat is b*T+t
    }
    if (tid < B_ * H_) zeroh[tid] = 0;     // bf16 zero page for h(-1)
    if (tid < 32 * FP_) flags[tid] = 0;
}

// ---------------- embedding gather -> bf16 X [T*B, H] (row = t*16+b) ----------------
__global__ void k_embed(const int* __restrict__ tokens, const float* __restrict__ emb,
                        unsigned short* __restrict__ X) {
    int tid = blockIdx.x * blockDim.x + threadIdx.x;
    if (tid >= M_ * H_) return;
    int row = tid >> 9, col = tid & 511;
    int t = row >> 4, b = row & 15;
    int tok = tokens[b * T_ + t];
    X[tid] = f2bf(emb[(size_t)tok * H_ + col]);
}

// ---------------- pack fp32 weight slab into MFMA B-frag order (bf16) ----------------
__global__ void k_pack(const float* __restrict__ src, int ld, int nvalid, int nkb,
                       int nchunks, unsigned short* __restrict__ dst) {
    int tid = blockIdx.x * blockDim.x + threadIdx.x;
    int lane = tid & 63, chunk = tid >> 6;
    if (chunk >= nchunks) return;
    int nt = chunk / nkb, kb = chunk % nkb;
    int n = nt * 16 + (lane & 15);
    int k = kb * 32 + ((lane >> 4) << 3);
    unsigned short vals[8];
    if (n < nvalid) {
#pragma unroll
        for (int j = 0; j < 8; ++j) vals[j] = f2bf(src[(size_t)(k + j) * ld + n]);
    } else {
#pragma unroll
        for (int j = 0; j < 8; ++j) vals[j] = 0;
    }
    *(short8*)(dst + (size_t)chunk * 512 + lane * 8) = *(short8*)vals;
}

// ---------------- big GEMM + bias: Z[M, 2048] = A[M,512](bf16) @ Bp + bias ----------------
__global__ __launch_bounds__(256, 2) void k_gemm_bias(
        const unsigned short* __restrict__ A, const unsigned short* __restrict__ Bp,
        const float* __restrict__ bias, float* __restrict__ C) {
    int bn = blockIdx.x, bm = blockIdx.y;
    int tid = threadIdx.x, lane = tid & 63, w = tid >> 6;
    int wm = w >> 1, wn = w & 1;
    int l15 = lane & 15, quad = lane >> 4;
    floatx4 acc[4][4];
#pragma unroll
    for (int i = 0; i < 4; ++i)
#pragma unroll
        for (int j = 0; j < 4; ++j) acc[i][j] = (floatx4){0.f, 0.f, 0.f, 0.f};
    const unsigned short* Abase = A + (size_t)(bm * 128 + wm * 64 + l15) * KH + quad * 8;
    int ntg0 = bn * 8 + wn * 4;
#pragma unroll 4
    for (int kb = 0; kb < NKB; ++kb) {
        short8 af[4], bf[4];
#pragma unroll
        for (int mt = 0; mt < 4; ++mt) af[mt] = *(const short8*)(Abase + mt * 16 * KH + kb * 32);
#pragma unroll
        for (int nt = 0; nt < 4; ++nt)
            bf[nt] = *(const short8*)(Bp + ((size_t)(ntg0 + nt) * NKB + kb) * 512 + lane * 8);
#pragma unroll
        for (int mt = 0; mt < 4; ++mt)
#pragma unroll
            for (int nt = 0; nt < 4; ++nt)
                acc[mt][nt] = __builtin_amdgcn_mfma_f32_16x16x32_bf16(af[mt], bf[nt], acc[mt][nt], 0, 0, 0);
    }
#pragma unroll
    for (int nt = 0; nt < 4; ++nt) {
        int col = bn * 128 + wn * 64 + nt * 16 + l15;
        float bv = bias[col];
#pragma unroll
        for (int mt = 0; mt < 4; ++mt) {
            int row0 = bm * 128 + wm * 64 + mt * 16 + quad * 4;
#pragma unroll
            for (int r = 0; r < 4; ++r)
                C[(size_t)(row0 + r) * N4H + col] = acc[mt][nt][r] + bv;
        }
    }
}

// ---------------- MEGA persistent kernel ----------------
// 256 blocks x 512 thr, 1 block/CU. __launch_bounds__(512, 2): 2 waves/SIMD ->
// 256-VGPR budget so bfr[32] (128 VGPR) is TRULY register-resident (rounds 2-5
// silently spilled it to scratch: VGPR_Count 92-120 < 128 needed; WRITE_SIZE
// matched the spill-region size. That spill reload was the ~10-16 us/step floor).
__global__ __launch_bounds__(512, 2) void k_mega(
        const float* __restrict__ Zpre1, const unsigned short* __restrict__ W1hP,
        const unsigned short* __restrict__ W2P, const float* __restrict__ b2,
        const unsigned short* __restrict__ zeroh,
        unsigned short* __restrict__ H1, unsigned short* __restrict__ H2,
        int* __restrict__ flags,
        const unsigned short* __restrict__ SWP, const float* __restrict__ sb,
        const int* __restrict__ lab_r,
        float* __restrict__ pm, float* __restrict__ ps, float* __restrict__ labv) {
    const int blk = blockIdx.x, tid = threadIdx.x;
    const int lane = tid & 63, w = tid >> 6;     // 8 waves
    const int l15 = lane & 15, quad = lane >> 4;
    __shared__ float zs[128 * 17];
    __shared__ float lmax[2][128];
    __shared__ float lsum[2][128];
    u64* H1u = (u64*)H1;
    u64* H2u = (u64*)H2;

    if (blk < 32) {
        // ================= recurrence (fence-free IC dataflow) =================
        const bool isL2 = blk >= 16;
        const int bj = isL2 ? blk - 16 : blk;
        const int g = w >> 1, half = w & 1;          // gate, col-half
        const int nt = g * 32 + bj * 2 + half;       // n-tile in packed weights

        short8 bfr[32];
        if (!isL2) {
#pragma unroll
            for (int kb = 0; kb < 16; ++kb)
                bfr[kb] = *(const short8*)(W1hP + (size_t)(nt * 16 + kb) * 512 + lane * 8);
        } else {
#pragma unroll
            for (int kb = 0; kb < 32; ++kb)
                bfr[kb] = *(const short8*)(W2P + (size_t)(nt * 32 + kb) * 512 + lane * 8);
        }
        const float b2c = isL2 ? b2[g * 512 + bj * 32 + half * 16 + l15] : 0.f;
        float creg = 0.f;

        for (int s = 0; s < T_; ++s) {
            if (w == 0 && (s > 0 || isL2)) {
                int tgt = 0x80000000;
                int* fp = flags;
                if (!isL2) {
                    if (lane < 16) { fp = flags + lane * FP_; tgt = s; }
                } else {
                    if (lane < 16) { fp = flags + lane * FP_; tgt = s + 1; }       // L1 flags
                    else if (lane < 32) { fp = flags + lane * FP_; tgt = s; }      // L2 flags
                }
                bool act = (!isL2 && lane < 16) || (isL2 && lane < 32);
                while (true) {
                    int v = act ? __hip_atomic_load(fp, __ATOMIC_RELAXED, __HIP_MEMORY_SCOPE_AGENT)
                                : 0x7fffffff;
                    if (__all(v >= tgt)) break;
                    __builtin_amdgcn_s_sleep(2);
                }
            }
            __syncthreads();

            if (!isL2) {
                const u64* hp = (s == 0) ? (const u64*)zeroh : H1u + (size_t)(s - 1) * 1024;
                const u64* fb = hp + l15 * 128 + quad * 2;
                u64 fa[32];
#pragma unroll
                for (int kb = 0; kb < 16; ++kb) {
                    fa[2 * kb]     = ld_ic(fb + kb * 8);
                    fa[2 * kb + 1] = ld_ic(fb + kb * 8 + 1);
                }
                floatx4 a0 = (floatx4){0.f,0.f,0.f,0.f}, a1 = (floatx4){0.f,0.f,0.f,0.f};
#pragma unroll
                for (int kb = 0; kb < 8; ++kb)
                    a0 = __builtin_amdgcn_mfma_f32_16x16x32_bf16(mk_frag(fa[2*kb], fa[2*kb+1]), bfr[kb], a0, 0, 0, 0);
#pragma unroll
                for (int kb = 8; kb < 16; ++kb)
                    a1 = __builtin_amdgcn_mfma_f32_16x16x32_bf16(mk_frag(fa[2*kb], fa[2*kb+1]), bfr[kb], a1, 0, 0, 0);
                const int colg = g * 512 + bj * 32 + half * 16 + l15;
                const int zcol = g * 32 + half * 16 + l15;
#pragma unroll
                for (int r = 0; r < 4; ++r) {
                    int b = quad * 4 + r;
                    zs[zcol * 17 + b] = a0[r] + a1[r] + Zpre1[(size_t)(s * 16 + b) * N4H + colg];
                }
            } else {
                const u64* h1p = H1u + (size_t)s * 1024;
                const u64* h2p = (s == 0) ? (const u64*)zeroh : H2u + (size_t)(s - 1) * 1024;
                const int fo = l15 * 128 + quad * 2;
                u64 fa[32];
                floatx4 a0 = (floatx4){0.f,0.f,0.f,0.f}, a1 = (floatx4){0.f,0.f,0.f,0.f};
#pragma unroll
                for (int kb = 0; kb < 16; ++kb) {
                    fa[2 * kb]     = ld_ic(h1p + fo + kb * 8);
                    fa[2 * kb + 1] = ld_ic(h1p + fo + kb * 8 + 1);
                }
#pragma unroll
                for (int kb = 0; kb < 16; ++kb)
                    a0 = __builtin_amdgcn_mfma_f32_16x16x32_bf16(mk_frag(fa[2*kb], fa[2*kb+1]), bfr[kb], a0, 0, 0, 0);
#pragma unroll
                for (int kb = 0; kb < 16; ++kb) {
                    fa[2 * kb]     = ld_ic(h2p + fo + kb * 8);
                    fa[2 * kb + 1] = ld_ic(h2p + fo + kb * 8 + 1);
                }
#pragma unroll
                for (int kb = 0; kb < 16; ++kb)
                    a1 = __builtin_amdgcn_mfma_f32_16x16x32_bf16(mk_frag(fa[2*kb], fa[2*kb+1]), bfr[16 + kb], a1, 0, 0, 0);
                const int zcol = g * 32 + half * 16 + l15;
#pragma unroll
                for (int r = 0; r < 4; ++r)
                    zs[zcol * 17 + quad * 4 + r] = a0[r] + a1[r] + b2c;
            }
            __syncthreads();

            {
                int u = tid >> 4, b = tid & 15;
                float zi = zs[(0 * 32 + u) * 17 + b];
                float zj = zs[(1 * 32 + u) * 17 + b];
                float zf = zs[(2 * 32 + u) * 17 + b];
                float zo = zs[(3 * 32 + u) * 17 + b];
                float si = 1.f / (1.f + __expf(-zi));
                float sf = 1.f / (1.f + __expf(-zf));
                float so = 1.f / (1.f + __expf(-zo));
                float cn = creg * sf + si * tanhf(zj);
                creg = cn;
                int hvi = (int)f2bf(tanhf(cn) * so);
                int lb = lane & 15;
                unsigned int h0 = (unsigned int)__shfl(hvi, lb);
                unsigned int h1v = (unsigned int)__shfl(hvi, lb + 16);
                unsigned int h2v = (unsigned int)__shfl(hvi, lb + 32);
                unsigned int h3v = (unsigned int)__shfl(hvi, lb + 48);
                if (lane < 16) {
                    u64 v = (u64)(h0 | (h1v << 16)) | ((u64)(h2v | (h3v << 16)) << 32);
                    u64* Hd = isL2 ? H2u : H1u;
                    st_ic(Hd + (size_t)(s * 16 + lane) * 128 + bj * 8 + w, v);
                }
            }
            __builtin_amdgcn_s_waitcnt(0x0F70);      // vmcnt(0): sc-stores ack'd at IC
            __syncthreads();
            if (tid == 0)
                __hip_atomic_store(flags + blk * FP_, s + 1, __ATOMIC_RELAXED,
                                   __HIP_MEMORY_SCOPE_AGENT);
        }
    } else {
        // ================= logits dataflow workers =================
        const int wid = blk - 32;
        const int wm = w >> 1, wn = w & 1;   // 4m x 2n wave grid; wave tile 32x64
        int done_seen = 0;
        for (int k = wid; k < NTILES; k += NWORK) {
            int bm = k / NBLK, bn = k - bm * NBLK;
            int tgt = bm * 8 + 8;            // need H2 rows through t = bm*8+7
            if (tgt > done_seen) {
                if (w == 0) {
                    int* fp = flags + (16 + (lane & 15)) * FP_;
                    while (true) {
                        int v = (lane < 16)
                            ? __hip_atomic_load(fp, __ATOMIC_RELAXED, __HIP_MEMORY_SCOPE_AGENT)
                            : 0x7fffffff;
                        if (__all(v >= tgt)) break;
                        __builtin_amdgcn_s_sleep(16);
                    }
                }
                __syncthreads();
                done_seen = tgt;
            }
            // ---- 128x128 tile GEMM: A = H2 (IC loads), B = SWP (cached) ----
            floatx4 acc[2][4];
#pragma unroll
            for (int i = 0; i < 2; ++i)
#pragma unroll
                for (int j = 0; j < 4; ++j) acc[i][j] = (floatx4){0.f, 0.f, 0.f, 0.f};
            const u64* Abase = H2u + (size_t)(bm * 128 + wm * 32 + l15) * 128 + quad * 2;
            int ntg0 = bn * 8 + wn * 4;
#pragma unroll 4
            for (int kb = 0; kb < NKB; ++kb) {
                u64 a0a = ld_ic(Abase + kb * 8);
                u64 a0b = ld_ic(Abase + kb * 8 + 1);
                u64 a1a = ld_ic(Abase + 16 * 128 + kb * 8);
                u64 a1b = ld_ic(Abase + 16 * 128 + kb * 8 + 1);
                short8 bf[4];
#pragma unroll
                for (int nt = 0; nt < 4; ++nt)
                    bf[nt] = *(const short8*)(SWP + ((size_t)(ntg0 + nt) * NKB + kb) * 512 + lane * 8);
                short8 af0 = mk_frag(a0a, a0b), af1 = mk_frag(a1a, a1b);
#pragma unroll
                for (int nt = 0; nt < 4; ++nt) {
                    acc[0][nt] = __builtin_amdgcn_mfma_f32_16x16x32_bf16(af0, bf[nt], acc[0][nt], 0, 0, 0);
                    acc[1][nt] = __builtin_amdgcn_mfma_f32_16x16x32_bf16(af1, bf[nt], acc[1][nt], 0, 0, 0);
                }
            }
            // ---- epilogue: bias, mask, per-row max/sumexp over this 128-col tile ----
            float bv[4]; int colg[4]; bool valid[4];
#pragma unroll
            for (int nt = 0; nt < 4; ++nt) {
                colg[nt] = bn * 128 + wn * 64 + nt * 16 + l15;
                valid[nt] = colg[nt] < V_;
                bv[nt] = valid[nt] ? sb[colg[nt]] : 0.f;
            }
#pragma unroll
            for (int mt = 0; mt < 2; ++mt) {
                float rmax[4], rsum[4];
#pragma unroll
                for (int r = 0; r < 4; ++r) {
                    float m = -3.0e38f;
#pragma unroll
                    for (int nt = 0; nt < 4; ++nt) {
                        float v = valid[nt] ? acc[mt][nt][r] + bv[nt] : -3.0e38f;
                        acc[mt][nt][r] = v;
                        m = fmaxf(m, v);
                    }
#pragma unroll
                    for (int d = 1; d < 16; d <<= 1) m = fmaxf(m, __shfl_xor(m, d, 16));
                    rmax[r] = m;
                    float sm = 0.f;
#pragma unroll
                    for (int nt = 0; nt < 4; ++nt)
                        if (valid[nt]) sm += __expf(acc[mt][nt][r] - m);
#pragma unroll
                    for (int d = 1; d < 16; d <<= 1) sm += __shfl_xor(sm, d, 16);
                    rsum[r] = sm;
                }
#pragma unroll
                for (int r = 0; r < 4; ++r) {
                    int lrow = wm * 32 + mt * 16 + quad * 4 + r;
                    int rowg = bm * 128 + lrow;
                    int lc = lab_r[rowg];
#pragma unroll
                    for (int nt = 0; nt < 4; ++nt)
                        if (valid[nt] && colg[nt] == lc) labv[rowg] = acc[mt][nt][r];
                    if (l15 == 0) { lmax[wn][lrow] = rmax[r]; lsum[wn][lrow] = rsum[r]; }
                }
            }
            __syncthreads();
            if (tid < 128) {
                float m0 = lmax[0][tid], m1 = lmax[1][tid];
                float m = fmaxf(m0, m1);
                float sm = 0.f;
                if (m0 > -1.0e30f) sm += lsum[0][tid] * __expf(m0 - m);
                if (m1 > -1.0e30f) sm += lsum[1][tid] * __expf(m1 - m);
                int rowg = bm * 128 + tid;
                pm[(size_t)rowg * NBLK + bn] = m;
                ps[(size_t)rowg * NBLK + bn] = sm;
            }
            __syncthreads();   // lmax/lsum reuse across tiles
        }
    }
}

// ---------------- per-row reduction over the 393 tiles ----------------
__global__ void k_rowreduce(const float* __restrict__ pm, const float* __restrict__ ps,
                            const float* __restrict__ labv, float* __restrict__ ll) {
    int row = blockIdx.x;
    int lane = threadIdx.x;  // 64
    const float* pmr = pm + (size_t)row * NBLK;
    const float* psr = ps + (size_t)row * NBLK;
    float m = -3.0e38f;
    for (int j = lane; j < NBLK; j += 64) m = fmaxf(m, pmr[j]);
#pragma unroll
    for (int d = 1; d < 64; d <<= 1) m = fmaxf(m, __shfl_xor(m, d, 64));
    float s = 0.f;
    for (int j = lane; j < NBLK; j += 64) s += psr[j] * __expf(pmr[j] - m);
#pragma unroll
    for (int d = 1; d < 64; d <<= 1) s += __shfl_xor(s, d, 64);
    if (lane == 0) ll[row] = labv[row] - m - logf(s);
}

__global__ void k_final(const float* __restrict__ ll, float* __restrict__ out) {
    int lane = threadIdx.x;  // 64
    float s = 0.f;
    for (int i = lane; i < M_; i += 64) s += ll[i];
#pragma unroll
    for (int d = 1; d < 64; d <<= 1) s += __shfl_xor(s, d, 64);
    if (lane == 0) out[0] = -s / (float)B_;
}

extern "C" void kernel_launch(void* const* d_in, const int* in_sizes, int n_in,
                              void* d_out, int out_size, void* d_ws, size_t ws_size,
                              hipStream_t stream) {
    const int* tokens = (const int*)d_in[0];
    const int* labels = (const int*)d_in[1];
    const float* emb = (const float*)d_in[2];
    const float* W1 = (const float*)d_in[3];
    const float* b1 = (const float*)d_in[4];
    const float* W2 = (const float*)d_in[5];
    const float* b2 = (const float*)d_in[6];
    const float* sw = (const float*)d_in[7];
    const float* sb = (const float*)d_in[8];
    float* out = (float*)d_out;

    char* ws = (char*)d_ws;
    size_t off = 0;
    auto alloc = [&](size_t bytes) {
        void* p = ws + off;
        off = (off + bytes + 255) & ~(size_t)255;
        return p;
    };
    unsigned short* X    = (unsigned short*)alloc((size_t)M_ * KH * 2);
    unsigned short* H1   = (unsigned short*)alloc((size_t)M_ * KH * 2);
    unsigned short* H2   = (unsigned short*)alloc((size_t)M_ * KH * 2);
    unsigned short* W1xP = (unsigned short*)alloc((size_t)N4H * KH * 2);
    unsigned short* W1hP = (unsigned short*)alloc((size_t)N4H * KH * 2);
    unsigned short* W2P  = (unsigned short*)alloc((size_t)N4H * KH * 2 * 2);  // K=1024
    unsigned short* SWP  = (unsigned short*)alloc((size_t)VP_ * KH * 2);
    float* Z     = (float*)alloc((size_t)M_ * N4H * 4);
    unsigned short* zeroh = (unsigned short*)alloc((size_t)B_ * H_ * 2);
    float* pm   = (float*)alloc((size_t)M_ * NBLK * 4);
    float* ps   = (float*)alloc((size_t)M_ * NBLK * 4);
    float* labv = (float*)alloc((size_t)M_ * 4);
    int*   lab_r = (int*)alloc((size_t)M_ * 4);
    float* ll   = (float*)alloc((size_t)M_ * 4);
    int*   flags = (int*)alloc((size_t)32 * FP_ * 4);

    // setup
    k_init<<<64, 256, 0, stream>>>(labels, lab_r, zeroh, flags);
    k_embed<<<(M_ * H_) / 256, 256, 0, stream>>>(tokens, emb, X);
    k_pack<<<512, 256, 0, stream>>>(W1,                      N4H, N4H, 16, 2048, W1xP);
    k_pack<<<512, 256, 0, stream>>>(W1 + (size_t)512 * N4H,  N4H, N4H, 16, 2048, W1hP);
    k_pack<<<1024, 256, 0, stream>>>(W2,                     N4H, N4H, 32, 4096, W2P);
    k_pack<<<12576, 256, 0, stream>>>(sw, V_, V_, 16, (VP_ / 16) * 16, SWP);

    // layer1 input pre-GEMM: Zpre1 = X @ W1x + b1
    k_gemm_bias<<<dim3(16, 16), 256, 0, stream>>>(X, W1xP, b1, Z);

    // fused persistent recurrence + dataflow logits (all 256 CUs busy, no spill)
    k_mega<<<256, 512, 0, stream>>>(Z, W1hP, W2P, b2, zeroh, H1, H2, flags,
                                    SWP, sb, lab_r, pm, ps, labv);

    // loss reduction
    k_rowreduce<<<M_, 64, 0, stream>>>(pm, ps, labv, ll);
    k_final<<<1, 64, 0, stream>>>(ll, out);
}

// Round 7
// 864.696 us; speedup vs baseline: 2.7506x; 2.7506x over previous
//
#include <hip/hip_runtime.h>

#define B_ 16
#define T_ 128
#define H_ 512
#define V_ 50257
#define VP_ 50304            // 393*128 (padded V)
#define NBLK 393             // VP_/128
#define M_ (B_*T_)           // 2048 rows (t*16+b)
#define N4H 2048             // 4*H
#define KH 512               // K of hidden GEMMs
#define NKB 16               // KH/32
#define FP_ 32               // flag pad (ints) = 128 B per flag line
#define NTILES (NBLK * 16)   // 6288 logits tiles
#define NWORK 224            // logits worker blocks (32..255)
#define NCHUNK (VP_ * 16 / 16)  // 50304 SWP pack chunks
#define HP_ 520              // LDS h pitch (ushorts): 1040 B, 8B-aligned, conflict-light

typedef __attribute__((ext_vector_type(8))) short short8;   // bf16x8 frag
typedef __attribute__((ext_vector_type(4))) float floatx4;
typedef unsigned long long u64;

static __device__ __forceinline__ unsigned short f2bf(float f) {
    unsigned int u = __builtin_bit_cast(unsigned int, f);
    unsigned int r = (u + 0x7FFFu + ((u >> 16) & 1u)) >> 16;
    return (unsigned short)r;
}
static __device__ __forceinline__ u64 ld_ic(const u64* p) {   // IC-coherent 8B load
    return __hip_atomic_load(p, __ATOMIC_RELAXED, __HIP_MEMORY_SCOPE_AGENT);
}
static __device__ __forceinline__ void st_ic(u64* p, u64 v) { // IC-coherent 8B store
    __hip_atomic_store(p, v, __ATOMIC_RELAXED, __HIP_MEMORY_SCOPE_AGENT);
}
static __device__ __forceinline__ short8 mk_frag(u64 a, u64 b) {
    union { u64 u[2]; short8 s8; } cv;
    cv.u[0] = a; cv.u[1] = b;
    return cv.s8;
}

// ---------------- init ----------------
__global__ void k_init(const int* __restrict__ labels, int* __restrict__ lab_r,
                       unsigned short* __restrict__ zeroh, int* __restrict__ flags) {
    int tid = blockIdx.x * blockDim.x + threadIdx.x;
    if (tid < M_) {
        int t = tid >> 4, b = tid & 15;
        lab_r[tid] = labels[b * T_ + t];   // row order is t*16+b; labels flat is b*T+t
    }
    if (tid < B_ * H_) zeroh[tid] = 0;     // bf16 zero page for h(-1)
    if (tid < 34 * FP_) flags[tid] = 0;    // 32 block flags + wdone line
}

// ---------------- embedding gather -> bf16 X [T*B, H] (row = t*16+b) ----------------
__global__ void k_embed(const int* __restrict__ tokens, const float* __restrict__ emb,
                        unsigned short* __restrict__ X) {
    int tid = blockIdx.x * blockDim.x + threadIdx.x;
    if (tid >= M_ * H_) return;
    int row = tid >> 9, col = tid & 511;
    int t = row >> 4, b = row & 15;
    int tok = tokens[b * T_ + t];
    X[tid] = f2bf(emb[(size_t)tok * H_ + col]);
}

// ---------------- pack fp32 weight slab into MFMA B-frag order (bf16) ----------------
__global__ void k_pack(const float* __restrict__ src, int ld, int nvalid, int nkb,
                       int nchunks, unsigned short* __restrict__ dst) {
    int tid = blockIdx.x * blockDim.x + threadIdx.x;
    int lane = tid & 63, chunk = tid >> 6;
    if (chunk >= nchunks) return;
    int nt = chunk / nkb, kb = chunk % nkb;
    int n = nt * 16 + (lane & 15);
    int k = kb * 32 + ((lane >> 4) << 3);
    unsigned short vals[8];
    if (n < nvalid) {
#pragma unroll
        for (int j = 0; j < 8; ++j) vals[j] = f2bf(src[(size_t)(k + j) * ld + n]);
    } else {
#pragma unroll
        for (int j = 0; j < 8; ++j) vals[j] = 0;
    }
    *(short8*)(dst + (size_t)chunk * 512 + lane * 8) = *(short8*)vals;
}

// ---------------- big GEMM + bias: Z[M, 2048] = A[M,512](bf16) @ Bp + bias ----------------
__global__ __launch_bounds__(256, 2) void k_gemm_bias(
        const unsigned short* __restrict__ A, const unsigned short* __restrict__ Bp,
        const float* __restrict__ bias, float* __restrict__ C) {
    int bn = blockIdx.x, bm = blockIdx.y;
    int tid = threadIdx.x, lane = tid & 63, w = tid >> 6;
    int wm = w >> 1, wn = w & 1;
    int l15 = lane & 15, quad = lane >> 4;
    floatx4 acc[4][4];
#pragma unroll
    for (int i = 0; i < 4; ++i)
#pragma unroll
        for (int j = 0; j < 4; ++j) acc[i][j] = (floatx4){0.f, 0.f, 0.f, 0.f};
    const unsigned short* Abase = A + (size_t)(bm * 128 + wm * 64 + l15) * KH + quad * 8;
    int ntg0 = bn * 8 + wn * 4;
#pragma unroll 4
    for (int kb = 0; kb < NKB; ++kb) {
        short8 af[4], bf[4];
#pragma unroll
        for (int mt = 0; mt < 4; ++mt) af[mt] = *(const short8*)(Abase + mt * 16 * KH + kb * 32);
#pragma unroll
        for (int nt = 0; nt < 4; ++nt)
            bf[nt] = *(const short8*)(Bp + ((size_t)(ntg0 + nt) * NKB + kb) * 512 + lane * 8);
#pragma unroll
        for (int mt = 0; mt < 4; ++mt)
#pragma unroll
            for (int nt = 0; nt < 4; ++nt)
                acc[mt][nt] = __builtin_amdgcn_mfma_f32_16x16x32_bf16(af[mt], bf[nt], acc[mt][nt], 0, 0, 0);
    }
#pragma unroll
    for (int nt = 0; nt < 4; ++nt) {
        int col = bn * 128 + wn * 64 + nt * 16 + l15;
        float bv = bias[col];
#pragma unroll
        for (int mt = 0; mt < 4; ++mt) {
            int row0 = bm * 128 + wm * 64 + mt * 16 + quad * 4;
#pragma unroll
            for (int r = 0; r < 4; ++r)
                C[(size_t)(row0 + r) * N4H + col] = acc[mt][nt][r] + bv;
        }
    }
}

// ---------------- MEGA persistent kernel ----------------
// 256 blocks x 512 thr, 1 block/CU.
// Blocks 0..15: L1 recurrence; 16..31: L2 recurrence; 32..255: logits workers.
// Key r7 change: all IC-atomic traffic deduplicated. Recurrence stages h into LDS
// with unique-address cooperative ld_ic (4-8/thread), MFMA A-frags from ds_read_b128.
// Workers: each wave owns a distinct 16-row m-strip (no duplicate A atomics), and
// pack SWP themselves (st_ic write-through + one-time 224-block barrier).
__global__ __launch_bounds__(512, 2) void k_mega(
        const float* __restrict__ Zpre1, const unsigned short* __restrict__ W1hP,
        const unsigned short* __restrict__ W2P, const float* __restrict__ b2,
        const unsigned short* __restrict__ zeroh,
        unsigned short* __restrict__ H1, unsigned short* __restrict__ H2,
        int* __restrict__ flags,
        const float* __restrict__ sw, unsigned short* __restrict__ SWP,
        const float* __restrict__ sb, const int* __restrict__ lab_r,
        float* __restrict__ pm, float* __restrict__ ps, float* __restrict__ labv) {
    const int blk = blockIdx.x, tid = threadIdx.x;
    const int lane = tid & 63, w = tid >> 6;     // 8 waves
    const int l15 = lane & 15, quad = lane >> 4;
    __shared__ unsigned short hs1[16 * HP_];     // staged h (16 rows x 512, padded)
    __shared__ unsigned short hs2[16 * HP_];
    __shared__ float zs[128 * 17];
    u64* H1u = (u64*)H1;
    u64* H2u = (u64*)H2;

    if (blk < 32) {
        // ================= recurrence =================
        const bool isL2 = blk >= 16;
        const int bj = isL2 ? blk - 16 : blk;
        const int g = w >> 1, half = w & 1;          // gate, col-half
        const int nt = g * 32 + bj * 2 + half;       // n-tile in packed weights

        short8 bfr[32];
        if (!isL2) {
#pragma unroll
            for (int kb = 0; kb < 16; ++kb)
                bfr[kb] = *(const short8*)(W1hP + (size_t)(nt * 16 + kb) * 512 + lane * 8);
        } else {
#pragma unroll
            for (int kb = 0; kb < 32; ++kb)
                bfr[kb] = *(const short8*)(W2P + (size_t)(nt * 32 + kb) * 512 + lane * 8);
        }
        const float b2c = isL2 ? b2[g * 512 + bj * 32 + half * 16 + l15] : 0.f;
        float creg = 0.f;

        for (int s = 0; s < T_; ++s) {
            // ---- wait for producers ----
            if (w == 0 && (s > 0 || isL2)) {
                int tgt = 0x80000000;
                int* fp = flags;
                if (!isL2) {
                    if (lane < 16) { fp = flags + lane * FP_; tgt = s; }
                } else {
                    if (lane < 16) { fp = flags + lane * FP_; tgt = s + 1; }       // L1 flags
                    else if (lane < 32) { fp = flags + lane * FP_; tgt = s; }      // L2 flags
                }
                bool act = (!isL2 && lane < 16) || (isL2 && lane < 32);
                while (true) {
                    int v = act ? __hip_atomic_load(fp, __ATOMIC_RELAXED, __HIP_MEMORY_SCOPE_AGENT)
                                : 0x7fffffff;
                    if (__all(v >= tgt)) break;
                    __builtin_amdgcn_s_sleep(1);
                }
            }
            __syncthreads();

            // ---- cooperative LDS staging of h (unique-address ld_ic, pipelined) ----
            if (!isL2) {
                const u64* src = (s == 0) ? (const u64*)zeroh : H1u + (size_t)(s - 1) * 1024;
#pragma unroll
                for (int j = 0; j < 4; ++j) {
                    int idx = j * 512 + tid;         // 0..2047 u64 words (16 rows x 128)
                    u64 v = ld_ic(src + idx);
                    *(u64*)(&hs1[(idx >> 7) * HP_ + (idx & 127) * 4]) = v;
                }
            } else {
                const u64* s1 = H1u + (size_t)s * 1024;
                const u64* s2 = (s == 0) ? (const u64*)zeroh : H2u + (size_t)(s - 1) * 1024;
#pragma unroll
                for (int j = 0; j < 4; ++j) {
                    int idx = j * 512 + tid;
                    u64 v = ld_ic(s1 + idx);
                    *(u64*)(&hs1[(idx >> 7) * HP_ + (idx & 127) * 4]) = v;
                }
#pragma unroll
                for (int j = 0; j < 4; ++j) {
                    int idx = j * 512 + tid;
                    u64 v = ld_ic(s2 + idx);
                    *(u64*)(&hs2[(idx >> 7) * HP_ + (idx & 127) * 4]) = v;
                }
            }
            __syncthreads();

            // ---- hidden GEMM from LDS frags ----
            if (!isL2) {
                floatx4 a0 = (floatx4){0.f,0.f,0.f,0.f}, a1 = (floatx4){0.f,0.f,0.f,0.f};
#pragma unroll
                for (int kb = 0; kb < 8; ++kb) {
                    short8 af = *(const short8*)(&hs1[l15 * HP_ + kb * 32 + quad * 8]);
                    a0 = __builtin_amdgcn_mfma_f32_16x16x32_bf16(af, bfr[kb], a0, 0, 0, 0);
                }
#pragma unroll
                for (int kb = 8; kb < 16; ++kb) {
                    short8 af = *(const short8*)(&hs1[l15 * HP_ + kb * 32 + quad * 8]);
                    a1 = __builtin_amdgcn_mfma_f32_16x16x32_bf16(af, bfr[kb], a1, 0, 0, 0);
                }
                const int colg = g * 512 + bj * 32 + half * 16 + l15;
                const int zcol = g * 32 + half * 16 + l15;
#pragma unroll
                for (int r = 0; r < 4; ++r) {
                    int b = quad * 4 + r;
                    zs[zcol * 17 + b] = a0[r] + a1[r] + Zpre1[(size_t)(s * 16 + b) * N4H + colg];
                }
            } else {
                floatx4 a0 = (floatx4){0.f,0.f,0.f,0.f}, a1 = (floatx4){0.f,0.f,0.f,0.f};
#pragma unroll
                for (int kb = 0; kb < 16; ++kb) {
                    short8 af = *(const short8*)(&hs1[l15 * HP_ + kb * 32 + quad * 8]);
                    a0 = __builtin_amdgcn_mfma_f32_16x16x32_bf16(af, bfr[kb], a0, 0, 0, 0);
                }
#pragma unroll
                for (int kb = 0; kb < 16; ++kb) {
                    short8 af = *(const short8*)(&hs2[l15 * HP_ + kb * 32 + quad * 8]);
                    a1 = __builtin_amdgcn_mfma_f32_16x16x32_bf16(af, bfr[16 + kb], a1, 0, 0, 0);
                }
                const int zcol = g * 32 + half * 16 + l15;
#pragma unroll
                for (int r = 0; r < 4; ++r)
                    zs[zcol * 17 + quad * 4 + r] = a0[r] + a1[r] + b2c;
            }
            __syncthreads();

            // ---- gate math ----
            {
                int u = tid >> 4, b = tid & 15;
                float zi = zs[(0 * 32 + u) * 17 + b];
                float zj = zs[(1 * 32 + u) * 17 + b];
                float zf = zs[(2 * 32 + u) * 17 + b];
                float zo = zs[(3 * 32 + u) * 17 + b];
                float si = 1.f / (1.f + __expf(-zi));
                float sf = 1.f / (1.f + __expf(-zf));
                float so = 1.f / (1.f + __expf(-zo));
                float cn = creg * sf + si * tanhf(zj);
                creg = cn;
                int hvi = (int)f2bf(tanhf(cn) * so);
                int lb = lane & 15;
                unsigned int h0 = (unsigned int)__shfl(hvi, lb);
                unsigned int h1v = (unsigned int)__shfl(hvi, lb + 16);
                unsigned int h2v = (unsigned int)__shfl(hvi, lb + 32);
                unsigned int h3v = (unsigned int)__shfl(hvi, lb + 48);
                if (lane < 16) {
                    u64 v = (u64)(h0 | (h1v << 16)) | ((u64)(h2v | (h3v << 16)) << 32);
                    u64* Hd = isL2 ? H2u : H1u;
                    st_ic(Hd + (size_t)(s * 16 + lane) * 128 + bj * 8 + w, v);
                }
            }
            __builtin_amdgcn_s_waitcnt(0x0F70);      // vmcnt(0): sc-stores ack'd at IC
            __syncthreads();
            if (tid == 0)
                __hip_atomic_store(flags + blk * FP_, s + 1, __ATOMIC_RELAXED,
                                   __HIP_MEMORY_SCOPE_AGENT);
        }
    } else {
        // ================= logits workers =================
        const int wid = blk - 32;
        int* wdone = flags + 32 * FP_;

        // ---- phase 0: cooperative SWP pack (write-through to IC) ----
        for (int t = 0; ; ++t) {
            int c = wid + NWORK * (8 * t + w);
            if (c >= NCHUNK) break;
            int cnt = c >> 4, ckb = c & 15;
            int n = cnt * 16 + l15;
            int kk = ckb * 32 + quad * 8;
            unsigned short vals[8];
            if (n < V_) {
#pragma unroll
                for (int j = 0; j < 8; ++j) vals[j] = f2bf(sw[(size_t)(kk + j) * V_ + n]);
            } else {
#pragma unroll
                for (int j = 0; j < 8; ++j) vals[j] = 0;
            }
            u64 v0 = (u64)vals[0] | ((u64)vals[1] << 16) | ((u64)vals[2] << 32) | ((u64)vals[3] << 48);
            u64 v1 = (u64)vals[4] | ((u64)vals[5] << 16) | ((u64)vals[6] << 32) | ((u64)vals[7] << 48);
            u64* dst = (u64*)(SWP + (size_t)c * 512 + lane * 8);
            st_ic(dst, v0);
            st_ic(dst + 1, v1);
        }
        __builtin_amdgcn_s_waitcnt(0x0F70);          // drain pack stores to IC
        __syncthreads();
        if (tid == 0)
            __hip_atomic_fetch_add(wdone, 1, __ATOMIC_RELAXED, __HIP_MEMORY_SCOPE_AGENT);
        if (w == 0) {
            while (true) {
                int v = (lane == 0)
                    ? __hip_atomic_load(wdone, __ATOMIC_RELAXED, __HIP_MEMORY_SCOPE_AGENT)
                    : 0x7fffffff;
                if (__all(v >= NWORK)) break;
                __builtin_amdgcn_s_sleep(8);
            }
        }
        __syncthreads();

        // ---- phase 1: consume tiles; wave w owns m-strip w (16 rows) x 128 cols ----
        int done_seen = 0;
        for (int k = wid; k < NTILES; k += NWORK) {
            int bm = k / NBLK, bn = k - bm * NBLK;
            int tgt = bm * 8 + 8;            // need H2 rows through t = bm*8+7
            if (tgt > done_seen) {
                if (w == 0) {
                    int* fp = flags + (16 + (lane & 15)) * FP_;
                    while (true) {
                        int v = (lane < 16)
                            ? __hip_atomic_load(fp, __ATOMIC_RELAXED, __HIP_MEMORY_SCOPE_AGENT)
                            : 0x7fffffff;
                        if (__all(v >= tgt)) break;
                        __builtin_amdgcn_s_sleep(8);
                    }
                }
                __syncthreads();
                done_seen = tgt;
            }
            floatx4 acc[8];
#pragma unroll
            for (int j = 0; j < 8; ++j) acc[j] = (floatx4){0.f, 0.f, 0.f, 0.f};
            const u64* Abase = H2u + (size_t)(bm * 128 + w * 16 + l15) * 128 + quad * 2;
            int ntg0 = bn * 8;
#pragma unroll 4
            for (int kb = 0; kb < NKB; ++kb) {
                u64 aa = ld_ic(Abase + kb * 8);
                u64 ab = ld_ic(Abase + kb * 8 + 1);
                short8 af = mk_frag(aa, ab);
#pragma unroll
                for (int nt = 0; nt < 8; ++nt) {
                    short8 bf = *(const short8*)(SWP + ((size_t)(ntg0 + nt) * NKB + kb) * 512 + lane * 8);
                    acc[nt] = __builtin_amdgcn_mfma_f32_16x16x32_bf16(af, bf, acc[nt], 0, 0, 0);
                }
            }
            // ---- wave-local epilogue (rows fully within wave; no LDS) ----
            float bv[8]; int colg[8]; bool valid[8];
#pragma unroll
            for (int nt = 0; nt < 8; ++nt) {
                colg[nt] = bn * 128 + nt * 16 + l15;
                valid[nt] = colg[nt] < V_;
                bv[nt] = valid[nt] ? sb[colg[nt]] : 0.f;
            }
#pragma unroll
            for (int r = 0; r < 4; ++r) {
                float m = -3.0e38f;
#pragma unroll
                for (int nt = 0; nt < 8; ++nt) {
                    float v = valid[nt] ? acc[nt][r] + bv[nt] : -3.0e38f;
                    acc[nt][r] = v;
                    m = fmaxf(m, v);
                }
#pragma unroll
                for (int d = 1; d < 16; d <<= 1) m = fmaxf(m, __shfl_xor(m, d, 16));
                float sm = 0.f;
#pragma unroll
                for (int nt = 0; nt < 8; ++nt)
                    if (valid[nt]) sm += __expf(acc[nt][r] - m);
#pragma unroll
                for (int d = 1; d < 16; d <<= 1) sm += __shfl_xor(sm, d, 16);
                int rowg = bm * 128 + w * 16 + quad * 4 + r;
                int lc = lab_r[rowg];
#pragma unroll
                for (int nt = 0; nt < 8; ++nt)
                    if (valid[nt] && colg[nt] == lc) labv[rowg] = acc[nt][r];
                if (l15 == 0) {
                    pm[(size_t)rowg * NBLK + bn] = m;
                    ps[(size_t)rowg * NBLK + bn] = sm;
                }
            }
        }
    }
}

// ---------------- per-row reduction over the 393 tiles ----------------
__global__ void k_rowreduce(const float* __restrict__ pm, const float* __restrict__ ps,
                            const float* __restrict__ labv, float* __restrict__ ll) {
    int row = blockIdx.x;
    int lane = threadIdx.x;  // 64
    const float* pmr = pm + (size_t)row * NBLK;
    const float* psr = ps + (size_t)row * NBLK;
    float m = -3.0e38f;
    for (int j = lane; j < NBLK; j += 64) m = fmaxf(m, pmr[j]);
#pragma unroll
    for (int d = 1; d < 64; d <<= 1) m = fmaxf(m, __shfl_xor(m, d, 64));
    float s = 0.f;
    for (int j = lane; j < NBLK; j += 64) s += psr[j] * __expf(pmr[j] - m);
#pragma unroll
    for (int d = 1; d < 64; d <<= 1) s += __shfl_xor(s, d, 64);
    if (lane == 0) ll[row] = labv[row] - m - logf(s);
}

__global__ void k_final(const float* __restrict__ ll, float* __restrict__ out) {
    int lane = threadIdx.x;  // 64
    float s = 0.f;
    for (int i = lane; i < M_; i += 64) s += ll[i];
#pragma unroll
    for (int d = 1; d < 64; d <<= 1) s += __shfl_xor(s, d, 64);
    if (lane == 0) out[0] = -s / (float)B_;
}

extern "C" void kernel_launch(void* const* d_in, const int* in_sizes, int n_in,
                              void* d_out, int out_size, void* d_ws, size_t ws_size,
                              hipStream_t stream) {
    const int* tokens = (const int*)d_in[0];
    const int* labels = (const int*)d_in[1];
    const float* emb = (const float*)d_in[2];
    const float* W1 = (const float*)d_in[3];
    const float* b1 = (const float*)d_in[4];
    const float* W2 = (const float*)d_in[5];
    const float* b2 = (const float*)d_in[6];
    const float* sw = (const float*)d_in[7];
    const float* sb = (const float*)d_in[8];
    float* out = (float*)d_out;

    char* ws = (char*)d_ws;
    size_t off = 0;
    auto alloc = [&](size_t bytes) {
        void* p = ws + off;
        off = (off + bytes + 255) & ~(size_t)255;
        return p;
    };
    unsigned short* X    = (unsigned short*)alloc((size_t)M_ * KH * 2);
    unsigned short* H1   = (unsigned short*)alloc((size_t)M_ * KH * 2);
    unsigned short* H2   = (unsigned short*)alloc((size_t)M_ * KH * 2);
    unsigned short* W1xP = (unsigned short*)alloc((size_t)N4H * KH * 2);
    unsigned short* W1hP = (unsigned short*)alloc((size_t)N4H * KH * 2);
    unsigned short* W2P  = (unsigned short*)alloc((size_t)N4H * KH * 2 * 2);  // K=1024
    unsigned short* SWP  = (unsigned short*)alloc((size_t)VP_ * KH * 2);
    float* Z     = (float*)alloc((size_t)M_ * N4H * 4);
    unsigned short* zeroh = (unsigned short*)alloc((size_t)B_ * H_ * 2);
    float* pm   = (float*)alloc((size_t)M_ * NBLK * 4);
    float* ps   = (float*)alloc((size_t)M_ * NBLK * 4);
    float* labv = (float*)alloc((size_t)M_ * 4);
    int*   lab_r = (int*)alloc((size_t)M_ * 4);
    float* ll   = (float*)alloc((size_t)M_ * 4);
    int*   flags = (int*)alloc((size_t)34 * FP_ * 4);

    // setup (SWP packing moved into k_mega workers)
    k_init<<<64, 256, 0, stream>>>(labels, lab_r, zeroh, flags);
    k_embed<<<(M_ * H_) / 256, 256, 0, stream>>>(tokens, emb, X);
    k_pack<<<512, 256, 0, stream>>>(W1,                      N4H, N4H, 16, 2048, W1xP);
    k_pack<<<512, 256, 0, stream>>>(W1 + (size_t)512 * N4H,  N4H, N4H, 16, 2048, W1hP);
    k_pack<<<1024, 256, 0, stream>>>(W2,                     N4H, N4H, 32, 4096, W2P);

    // layer1 input pre-GEMM: Zpre1 = X @ W1x + b1
    k_gemm_bias<<<dim3(16, 16), 256, 0, stream>>>(X, W1xP, b1, Z);

    // fused persistent recurrence + dataflow logits (dedup'd IC atomics)
    k_mega<<<256, 512, 0, stream>>>(Z, W1hP, W2P, b2, zeroh, H1, H2, flags,
                                    sw, SWP, sb, lab_r, pm, ps, labv);

    // loss reduction
    k_rowreduce<<<M_, 64, 0, stream>>>(pm, ps, labv, ll);
    k_final<<<1, 64, 0, stream>>>(ll, out);
}

// Round 8
// 765.017 us; speedup vs baseline: 3.1090x; 1.1303x over previous
//
#include <hip/hip_runtime.h>

#define B_ 16
#define T_ 128
#define H_ 512
#define V_ 50257
#define VP_ 50304            // 393*128 (padded V)
#define NBLK 393             // VP_/128
#define M_ (B_*T_)           // 2048 rows (t*16+b)
#define N4H 2048             // 4*H
#define KH 512               // K of hidden GEMMs
#define NKB 16               // KH/32
#define FP_ 32               // flag pad (ints) = 128 B per flag line
#define NTILES (NBLK * 16)   // 6288 logits tiles
#define NWORK 224            // logits worker blocks (32..255)
#define NCHUNK (VP_ * 16 / 16)  // 50304 SWP pack chunks
#define HP_ 520              // LDS h pitch (ushorts): 1040 B, 8B-aligned

typedef __attribute__((ext_vector_type(8))) short short8;   // bf16x8 frag
typedef __attribute__((ext_vector_type(4))) float floatx4;
typedef unsigned long long u64;

static __device__ __forceinline__ unsigned short f2bf(float f) {
    unsigned int u = __builtin_bit_cast(unsigned int, f);
    unsigned int r = (u + 0x7FFFu + ((u >> 16) & 1u)) >> 16;
    return (unsigned short)r;
}
// write-through store, visible at IC before the flag (producers only)
static __device__ __forceinline__ void st_ic(u64* p, u64 v) {
    __hip_atomic_store(p, v, __ATOMIC_RELAXED, __HIP_MEMORY_SCOPE_AGENT);
}

// ---------------- init ----------------
__global__ void k_init(const int* __restrict__ labels, int* __restrict__ lab_r,
                       unsigned short* __restrict__ zeroh, int* __restrict__ flags) {
    int tid = blockIdx.x * blockDim.x + threadIdx.x;
    if (tid < M_) {
        int t = tid >> 4, b = tid & 15;
        lab_r[tid] = labels[b * T_ + t];   // row order is t*16+b; labels flat is b*T+t
    }
    if (tid < B_ * H_) zeroh[tid] = 0;     // bf16 zero page for h(-1)
    if (tid < 34 * FP_) flags[tid] = 0;    // 32 block flags + wdone line
}

// ---------------- embedding gather -> bf16 X [T*B, H] (row = t*16+b) ----------------
__global__ void k_embed(const int* __restrict__ tokens, const float* __restrict__ emb,
                        unsigned short* __restrict__ X) {
    int tid = blockIdx.x * blockDim.x + threadIdx.x;
    if (tid >= M_ * H_) return;
    int row = tid >> 9, col = tid & 511;
    int t = row >> 4, b = row & 15;
    int tok = tokens[b * T_ + t];
    X[tid] = f2bf(emb[(size_t)tok * H_ + col]);
}

// ---------------- pack fp32 weight slab into MFMA B-frag order (bf16) ----------------
__global__ void k_pack(const float* __restrict__ src, int ld, int nvalid, int nkb,
                       int nchunks, unsigned short* __restrict__ dst) {
    int tid = blockIdx.x * blockDim.x + threadIdx.x;
    int lane = tid & 63, chunk = tid >> 6;
    if (chunk >= nchunks) return;
    int nt = chunk / nkb, kb = chunk % nkb;
    int n = nt * 16 + (lane & 15);
    int k = kb * 32 + ((lane >> 4) << 3);
    unsigned short vals[8];
    if (n < nvalid) {
#pragma unroll
        for (int j = 0; j < 8; ++j) vals[j] = f2bf(src[(size_t)(k + j) * ld + n]);
    } else {
#pragma unroll
        for (int j = 0; j < 8; ++j) vals[j] = 0;
    }
    *(short8*)(dst + (size_t)chunk * 512 + lane * 8) = *(short8*)vals;
}

// ---------------- big GEMM + bias: Z[M, 2048] = A[M,512](bf16) @ Bp + bias ----------------
__global__ __launch_bounds__(256, 2) void k_gemm_bias(
        const unsigned short* __restrict__ A, const unsigned short* __restrict__ Bp,
        const float* __restrict__ bias, float* __restrict__ C) {
    int bn = blockIdx.x, bm = blockIdx.y;
    int tid = threadIdx.x, lane = tid & 63, w = tid >> 6;
    int wm = w >> 1, wn = w & 1;
    int l15 = lane & 15, quad = lane >> 4;
    floatx4 acc[4][4];
#pragma unroll
    for (int i = 0; i < 4; ++i)
#pragma unroll
        for (int j = 0; j < 4; ++j) acc[i][j] = (floatx4){0.f, 0.f, 0.f, 0.f};
    const unsigned short* Abase = A + (size_t)(bm * 128 + wm * 64 + l15) * KH + quad * 8;
    int ntg0 = bn * 8 + wn * 4;
#pragma unroll 4
    for (int kb = 0; kb < NKB; ++kb) {
        short8 af[4], bf[4];
#pragma unroll
        for (int mt = 0; mt < 4; ++mt) af[mt] = *(const short8*)(Abase + mt * 16 * KH + kb * 32);
#pragma unroll
        for (int nt = 0; nt < 4; ++nt)
            bf[nt] = *(const short8*)(Bp + ((size_t)(ntg0 + nt) * NKB + kb) * 512 + lane * 8);
#pragma unroll
        for (int mt = 0; mt < 4; ++mt)
#pragma unroll
            for (int nt = 0; nt < 4; ++nt)
                acc[mt][nt] = __builtin_amdgcn_mfma_f32_16x16x32_bf16(af[mt], bf[nt], acc[mt][nt], 0, 0, 0);
    }
#pragma unroll
    for (int nt = 0; nt < 4; ++nt) {
        int col = bn * 128 + wn * 64 + nt * 16 + l15;
        float bv = bias[col];
#pragma unroll
        for (int mt = 0; mt < 4; ++mt) {
            int row0 = bm * 128 + wm * 64 + mt * 16 + quad * 4;
#pragma unroll
            for (int r = 0; r < 4; ++r)
                C[(size_t)(row0 + r) * N4H + col] = acc[mt][nt][r] + bv;
        }
    }
}

// ---------------- MEGA persistent kernel ----------------
// 256 blocks x 512 thr, 1 block/CU. Blocks 0..15: L1 recurrence; 16..31: L2; 32..255:
// logits workers. r8: ALL reader-side traffic uses plain cached 16B loads (safe: every
// cross-block read is flag-gated => first touch on the reading XCD happens post-write;
// dispatch-start acquire invalidated any pre-kernel lines). Producers keep st_ic
// (write-through, visible at IC before flag). This removes ~100M 8B coherent IC
// requests that bounded r7 at 670 us. Recurrence weights built directly from fp32 W.
__global__ __launch_bounds__(512, 2) void k_mega(
        const float* __restrict__ Zpre1, const float* __restrict__ W1,
        const float* __restrict__ W2, const float* __restrict__ b2,
        const unsigned short* __restrict__ zeroh,
        unsigned short* __restrict__ H1, unsigned short* __restrict__ H2,
        int* __restrict__ flags,
        const float* __restrict__ sw, unsigned short* __restrict__ SWP,
        const float* __restrict__ sb, const int* __restrict__ lab_r,
        float* __restrict__ pm, float* __restrict__ ps, float* __restrict__ labv) {
    const int blk = blockIdx.x, tid = threadIdx.x;
    const int lane = tid & 63, w = tid >> 6;     // 8 waves
    const int l15 = lane & 15, quad = lane >> 4;
    __shared__ unsigned short hs1[16 * HP_];     // staged h (16 rows x 512, padded)
    __shared__ unsigned short hs2[16 * HP_];
    __shared__ float zs[128 * 17];
    u64* H1u = (u64*)H1;
    u64* H2u = (u64*)H2;

    if (blk < 32) {
        // ================= recurrence =================
        const bool isL2 = blk >= 16;
        const int bj = isL2 ? blk - 16 : blk;
        const int g = w >> 1, half = w & 1;          // gate, col-half
        const int nt = g * 32 + bj * 2 + half;       // n-tile
        const int colg = g * 512 + bj * 32 + half * 16 + l15;

        // build register-resident B fragments directly from fp32 weights
        short8 bfr[32];
        {
            unsigned short vals[8];
            if (!isL2) {
#pragma unroll
                for (int kb = 0; kb < 16; ++kb) {
#pragma unroll
                    for (int j = 0; j < 8; ++j)
                        vals[j] = f2bf(W1[(size_t)(512 + kb * 32 + quad * 8 + j) * N4H + nt * 16 + l15]);
                    bfr[kb] = *(short8*)vals;
                }
            } else {
#pragma unroll
                for (int kb = 0; kb < 32; ++kb) {
#pragma unroll
                    for (int j = 0; j < 8; ++j)
                        vals[j] = f2bf(W2[(size_t)(kb * 32 + quad * 8 + j) * N4H + nt * 16 + l15]);
                    bfr[kb] = *(short8*)vals;
                }
            }
        }
        const float b2c = isL2 ? b2[colg] : 0.f;
        float creg = 0.f;

        for (int s = 0; s < T_; ++s) {
            // ---- Zpre prefetch (independent of flags; off critical path) ----
            float zpre[4];
            if (!isL2) {
#pragma unroll
                for (int r = 0; r < 4; ++r)
                    zpre[r] = Zpre1[(size_t)(s * 16 + quad * 4 + r) * N4H + colg];
            }
            // ---- wait for producers ----
            if (w == 0 && (s > 0 || isL2)) {
                int tgt = 0x80000000;
                int* fp = flags;
                if (!isL2) {
                    if (lane < 16) { fp = flags + lane * FP_; tgt = s; }
                } else {
                    if (lane < 16) { fp = flags + lane * FP_; tgt = s + 1; }       // L1 flags
                    else if (lane < 32) { fp = flags + lane * FP_; tgt = s; }      // L2 flags
                }
                bool act = (!isL2 && lane < 16) || (isL2 && lane < 32);
                while (true) {
                    int v = act ? __hip_atomic_load(fp, __ATOMIC_RELAXED, __HIP_MEMORY_SCOPE_AGENT)
                                : 0x7fffffff;
                    if (__all(v >= tgt)) break;
                    __builtin_amdgcn_s_sleep(1);
                }
            }
            __syncthreads();

            // ---- cooperative LDS staging of h (plain cached 16B loads) ----
            if (!isL2) {
                const short8* src = (const short8*)((s == 0) ? zeroh
                                       : H1 + (size_t)(s - 1) * B_ * H_);
#pragma unroll
                for (int j = 0; j < 2; ++j) {
                    int idx = j * 512 + tid;         // 0..1023 (16 rows x 64 short8)
                    short8 v = src[idx];
                    *(short8*)(&hs1[(idx >> 6) * HP_ + (idx & 63) * 8]) = v;
                }
            } else {
                const short8* s1 = (const short8*)(H1 + (size_t)s * B_ * H_);
                const short8* s2 = (const short8*)((s == 0) ? zeroh
                                       : H2 + (size_t)(s - 1) * B_ * H_);
#pragma unroll
                for (int j = 0; j < 2; ++j) {
                    int idx = j * 512 + tid;
                    short8 v = s1[idx];
                    *(short8*)(&hs1[(idx >> 6) * HP_ + (idx & 63) * 8]) = v;
                }
#pragma unroll
                for (int j = 0; j < 2; ++j) {
                    int idx = j * 512 + tid;
                    short8 v = s2[idx];
                    *(short8*)(&hs2[(idx >> 6) * HP_ + (idx & 63) * 8]) = v;
                }
            }
            __syncthreads();

            // ---- hidden GEMM from LDS frags ----
            if (!isL2) {
                floatx4 a0 = (floatx4){0.f,0.f,0.f,0.f}, a1 = (floatx4){0.f,0.f,0.f,0.f};
#pragma unroll
                for (int kb = 0; kb < 8; ++kb) {
                    short8 af = *(const short8*)(&hs1[l15 * HP_ + kb * 32 + quad * 8]);
                    a0 = __builtin_amdgcn_mfma_f32_16x16x32_bf16(af, bfr[kb], a0, 0, 0, 0);
                }
#pragma unroll
                for (int kb = 8; kb < 16; ++kb) {
                    short8 af = *(const short8*)(&hs1[l15 * HP_ + kb * 32 + quad * 8]);
                    a1 = __builtin_amdgcn_mfma_f32_16x16x32_bf16(af, bfr[kb], a1, 0, 0, 0);
                }
                const int zcol = g * 32 + half * 16 + l15;
#pragma unroll
                for (int r = 0; r < 4; ++r)
                    zs[zcol * 17 + quad * 4 + r] = a0[r] + a1[r] + zpre[r];
            } else {
                floatx4 a0 = (floatx4){0.f,0.f,0.f,0.f}, a1 = (floatx4){0.f,0.f,0.f,0.f};
#pragma unroll
                for (int kb = 0; kb < 16; ++kb) {
                    short8 af = *(const short8*)(&hs1[l15 * HP_ + kb * 32 + quad * 8]);
                    a0 = __builtin_amdgcn_mfma_f32_16x16x32_bf16(af, bfr[kb], a0, 0, 0, 0);
                }
#pragma unroll
                for (int kb = 0; kb < 16; ++kb) {
                    short8 af = *(const short8*)(&hs2[l15 * HP_ + kb * 32 + quad * 8]);
                    a1 = __builtin_amdgcn_mfma_f32_16x16x32_bf16(af, bfr[16 + kb], a1, 0, 0, 0);
                }
                const int zcol = g * 32 + half * 16 + l15;
#pragma unroll
                for (int r = 0; r < 4; ++r)
                    zs[zcol * 17 + quad * 4 + r] = a0[r] + a1[r] + b2c;
            }
            __syncthreads();

            // ---- gate math ----
            {
                int u = tid >> 4, b = tid & 15;
                float zi = zs[(0 * 32 + u) * 17 + b];
                float zj = zs[(1 * 32 + u) * 17 + b];
                float zf = zs[(2 * 32 + u) * 17 + b];
                float zo = zs[(3 * 32 + u) * 17 + b];
                float si = 1.f / (1.f + __expf(-zi));
                float sf = 1.f / (1.f + __expf(-zf));
                float so = 1.f / (1.f + __expf(-zo));
                float cn = creg * sf + si * tanhf(zj);
                creg = cn;
                int hvi = (int)f2bf(tanhf(cn) * so);
                int lb = lane & 15;
                unsigned int h0 = (unsigned int)__shfl(hvi, lb);
                unsigned int h1v = (unsigned int)__shfl(hvi, lb + 16);
                unsigned int h2v = (unsigned int)__shfl(hvi, lb + 32);
                unsigned int h3v = (unsigned int)__shfl(hvi, lb + 48);
                if (lane < 16) {
                    u64 v = (u64)(h0 | (h1v << 16)) | ((u64)(h2v | (h3v << 16)) << 32);
                    u64* Hd = isL2 ? H2u : H1u;
                    st_ic(Hd + (size_t)(s * 16 + lane) * 128 + bj * 8 + w, v);
                }
            }
            __builtin_amdgcn_s_waitcnt(0x0F70);      // vmcnt(0): sc-stores ack'd at IC
            __syncthreads();
            if (tid == 0)
                __hip_atomic_store(flags + blk * FP_, s + 1, __ATOMIC_RELAXED,
                                   __HIP_MEMORY_SCOPE_AGENT);
        }
    } else {
        // ================= logits workers =================
        const int wid = blk - 32;
        int* wdone = flags + 32 * FP_;

        // ---- phase 0: cooperative SWP pack (st_ic write-through to IC) ----
        for (int t = 0; ; ++t) {
            int c = wid + NWORK * (8 * t + w);
            if (c >= NCHUNK) break;
            int cnt = c >> 4, ckb = c & 15;
            int n = cnt * 16 + l15;
            int kk = ckb * 32 + quad * 8;
            unsigned short vals[8];
            if (n < V_) {
#pragma unroll
                for (int j = 0; j < 8; ++j) vals[j] = f2bf(sw[(size_t)(kk + j) * V_ + n]);
            } else {
#pragma unroll
                for (int j = 0; j < 8; ++j) vals[j] = 0;
            }
            u64 v0 = (u64)vals[0] | ((u64)vals[1] << 16) | ((u64)vals[2] << 32) | ((u64)vals[3] << 48);
            u64 v1 = (u64)vals[4] | ((u64)vals[5] << 16) | ((u64)vals[6] << 32) | ((u64)vals[7] << 48);
            u64* dst = (u64*)(SWP + (size_t)c * 512 + lane * 8);
            st_ic(dst, v0);
            st_ic(dst + 1, v1);
        }
        __builtin_amdgcn_s_waitcnt(0x0F70);          // drain pack stores to IC
        __syncthreads();
        if (tid == 0)
            __hip_atomic_fetch_add(wdone, 1, __ATOMIC_RELAXED, __HIP_MEMORY_SCOPE_AGENT);
        if (w == 0) {
            while (true) {
                int v = (lane == 0)
                    ? __hip_atomic_load(wdone, __ATOMIC_RELAXED, __HIP_MEMORY_SCOPE_AGENT)
                    : 0x7fffffff;
                if (__all(v >= NWORK)) break;
                __builtin_amdgcn_s_sleep(8);
            }
        }
        __syncthreads();

        // ---- phase 1: consume tiles; wave w owns m-strip w (16 rows) x 128 cols ----
        int done_seen = 0;
        for (int k = wid; k < NTILES; k += NWORK) {
            int bm = k / NBLK, bn = k - bm * NBLK;
            int tgt = bm * 8 + 8;            // need H2 rows through t = bm*8+7
            if (tgt > done_seen) {
                if (w == 0) {
                    int* fp = flags + (16 + (lane & 15)) * FP_;
                    while (true) {
                        int v = (lane < 16)
                            ? __hip_atomic_load(fp, __ATOMIC_RELAXED, __HIP_MEMORY_SCOPE_AGENT)
                            : 0x7fffffff;
                        if (__all(v >= tgt)) break;
                        __builtin_amdgcn_s_sleep(8);
                    }
                }
                __syncthreads();
                done_seen = tgt;
            }
            floatx4 acc[8];
#pragma unroll
            for (int j = 0; j < 8; ++j) acc[j] = (floatx4){0.f, 0.f, 0.f, 0.f};
            // A via plain cached 16B loads (flag-gated => coherent-by-construction)
            const short8* Abase = (const short8*)(H2 + (size_t)(bm * 128 + w * 16 + l15) * KH) + quad;
            int ntg0 = bn * 8;
#pragma unroll 4
            for (int kb = 0; kb < NKB; ++kb) {
                short8 af = Abase[kb * 4];
#pragma unroll
                for (int nt = 0; nt < 8; ++nt) {
                    short8 bf = *(const short8*)(SWP + ((size_t)(ntg0 + nt) * NKB + kb) * 512 + lane * 8);
                    acc[nt] = __builtin_amdgcn_mfma_f32_16x16x32_bf16(af, bf, acc[nt], 0, 0, 0);
                }
            }
            // ---- wave-local epilogue ----
            float bv[8]; int colg[8]; bool valid[8];
#pragma unroll
            for (int nt = 0; nt < 8; ++nt) {
                colg[nt] = bn * 128 + nt * 16 + l15;
                valid[nt] = colg[nt] < V_;
                bv[nt] = valid[nt] ? sb[colg[nt]] : 0.f;
            }
#pragma unroll
            for (int r = 0; r < 4; ++r) {
                float m = -3.0e38f;
#pragma unroll
                for (int nt = 0; nt < 8; ++nt) {
                    float v = valid[nt] ? acc[nt][r] + bv[nt] : -3.0e38f;
                    acc[nt][r] = v;
                    m = fmaxf(m, v);
                }
#pragma unroll
                for (int d = 1; d < 16; d <<= 1) m = fmaxf(m, __shfl_xor(m, d, 16));
                float sm = 0.f;
#pragma unroll
                for (int nt = 0; nt < 8; ++nt)
                    if (valid[nt]) sm += __expf(acc[nt][r] - m);
#pragma unroll
                for (int d = 1; d < 16; d <<= 1) sm += __shfl_xor(sm, d, 16);
                int rowg = bm * 128 + w * 16 + quad * 4 + r;
                int lc = lab_r[rowg];
#pragma unroll
                for (int nt = 0; nt < 8; ++nt)
                    if (valid[nt] && colg[nt] == lc) labv[rowg] = acc[nt][r];
                if (l15 == 0) {
                    pm[(size_t)rowg * NBLK + bn] = m;
                    ps[(size_t)rowg * NBLK + bn] = sm;
                }
            }
        }
    }
}

// ---------------- per-row reduction over the 393 tiles ----------------
__global__ void k_rowreduce(const float* __restrict__ pm, const float* __restrict__ ps,
                            const float* __restrict__ labv, float* __restrict__ ll) {
    int row = blockIdx.x;
    int lane = threadIdx.x;  // 64
    const float* pmr = pm + (size_t)row * NBLK;
    const float* psr = ps + (size_t)row * NBLK;
    float m = -3.0e38f;
    for (int j = lane; j < NBLK; j += 64) m = fmaxf(m, pmr[j]);
#pragma unroll
    for (int d = 1; d < 64; d <<= 1) m = fmaxf(m, __shfl_xor(m, d, 64));
    float s = 0.f;
    for (int j = lane; j < NBLK; j += 64) s += psr[j] * __expf(pmr[j] - m);
#pragma unroll
    for (int d = 1; d < 64; d <<= 1) s += __shfl_xor(s, d, 64);
    if (lane == 0) ll[row] = labv[row] - m - logf(s);
}

__global__ void k_final(const float* __restrict__ ll, float* __restrict__ out) {
    int lane = threadIdx.x;  // 64
    float s = 0.f;
    for (int i = lane; i < M_; i += 64) s += ll[i];
#pragma unroll
    for (int d = 1; d < 64; d <<= 1) s += __shfl_xor(s, d, 64);
    if (lane == 0) out[0] = -s / (float)B_;
}

extern "C" void kernel_launch(void* const* d_in, const int* in_sizes, int n_in,
                              void* d_out, int out_size, void* d_ws, size_t ws_size,
                              hipStream_t stream) {
    const int* tokens = (const int*)d_in[0];
    const int* labels = (const int*)d_in[1];
    const float* emb = (const float*)d_in[2];
    const float* W1 = (const float*)d_in[3];
    const float* b1 = (const float*)d_in[4];
    const float* W2 = (const float*)d_in[5];
    const float* b2 = (const float*)d_in[6];
    const float* sw = (const float*)d_in[7];
    const float* sb = (const float*)d_in[8];
    float* out = (float*)d_out;

    char* ws = (char*)d_ws;
    size_t off = 0;
    auto alloc = [&](size_t bytes) {
        void* p = ws + off;
        off = (off + bytes + 255) & ~(size_t)255;
        return p;
    };
    unsigned short* X    = (unsigned short*)alloc((size_t)M_ * KH * 2);
    unsigned short* H1   = (unsigned short*)alloc((size_t)M_ * KH * 2);
    unsigned short* H2   = (unsigned short*)alloc((size_t)M_ * KH * 2);
    unsigned short* W1xP = (unsigned short*)alloc((size_t)N4H * KH * 2);
    unsigned short* SWP  = (unsigned short*)alloc((size_t)VP_ * KH * 2);
    float* Z     = (float*)alloc((size_t)M_ * N4H * 4);
    unsigned short* zeroh = (unsigned short*)alloc((size_t)B_ * H_ * 2);
    float* pm   = (float*)alloc((size_t)M_ * NBLK * 4);
    float* ps   = (float*)alloc((size_t)M_ * NBLK * 4);
    float* labv = (float*)alloc((size_t)M_ * 4);
    int*   lab_r = (int*)alloc((size_t)M_ * 4);
    float* ll   = (float*)alloc((size_t)M_ * 4);
    int*   flags = (int*)alloc((size_t)34 * FP_ * 4);

    // setup (W1h/W2 packing folded into k_mega; SWP packed by workers)
    k_init<<<64, 256, 0, stream>>>(labels, lab_r, zeroh, flags);
    k_embed<<<(M_ * H_) / 256, 256, 0, stream>>>(tokens, emb, X);
    k_pack<<<512, 256, 0, stream>>>(W1, N4H, N4H, 16, 2048, W1xP);

    // layer1 input pre-GEMM: Zpre1 = X @ W1x + b1
    k_gemm_bias<<<dim3(16, 16), 256, 0, stream>>>(X, W1xP, b1, Z);

    // fused persistent recurrence + dataflow logits (plain cached reads, st_ic writes)
    k_mega<<<256, 512, 0, stream>>>(Z, W1, W2, b2, zeroh, H1, H2, flags,
                                    sw, SWP, sb, lab_r, pm, ps, labv);

    // loss reduction
    k_rowreduce<<<M_, 64, 0, stream>>>(pm, ps, labv, ll);
    k_final<<<1, 64, 0, stream>>>(ll, out);
}